// Round 1
// baseline (10648.869 us; speedup 1.0000x reference)
//
#include <hip/hip_runtime.h>
#include <cstdint>
#include <cstddef>

#define H 8192
#define NNZ 1000000
#define B 128
#define T 64

// ---------------- CSR build ----------------
__global__ void hist_kernel(const int* __restrict__ rows, int nnz, int* __restrict__ count) {
    int j = blockIdx.x * blockDim.x + threadIdx.x;
    if (j < nnz) atomicAdd(&count[rows[j]], 1);
}

// grid=2 blocks, 1024 threads: block 0 scans array A, block 1 scans array B.
__global__ void scan_kernel(const int* __restrict__ cnt0, int* __restrict__ rp0, int* __restrict__ cur0,
                            const int* __restrict__ cnt1, int* __restrict__ rp1, int* __restrict__ cur1) {
    const int* cnt = (blockIdx.x == 0) ? cnt0 : cnt1;
    int* rp  = (blockIdx.x == 0) ? rp0 : rp1;
    int* cur = (blockIdx.x == 0) ? cur0 : cur1;
    __shared__ int buf[1024];
    __shared__ int carry;
    int tid = threadIdx.x;
    if (tid == 0) carry = 0;
    __syncthreads();
    for (int base = 0; base < H; base += 1024) {
        int v = cnt[base + tid];
        buf[tid] = v;
        __syncthreads();
        for (int off = 1; off < 1024; off <<= 1) {
            int t = (tid >= off) ? buf[tid - off] : 0;
            __syncthreads();
            buf[tid] += t;
            __syncthreads();
        }
        int incl = buf[tid];
        int excl = incl - v;
        int c = carry;
        rp[base + tid]  = c + excl;
        cur[base + tid] = c + excl;
        __syncthreads();
        if (tid == 1023) carry = c + incl;
        __syncthreads();
    }
    if (tid == 0) rp[H] = carry;
}

__global__ void scatter_kernel(const int* __restrict__ rows, const int* __restrict__ cols,
                               const float* __restrict__ vals, int nnz,
                               int* __restrict__ cursor, int* __restrict__ ocol, float* __restrict__ oval) {
    int j = blockIdx.x * blockDim.x + threadIdx.x;
    if (j < nnz) {
        int r = rows[j];
        int p = atomicAdd(&cursor[r], 1);
        ocol[p] = cols[j];
        oval[p] = vals[j];
    }
}

// ---------------- transpose src[R][C] -> dst[C][R]  (R,C multiples of 32) ----------------
__global__ void transpose_kernel(const float* __restrict__ src, float* __restrict__ dst,
                                 int R, int C) {
    __shared__ float tile[32][33];
    int c0 = blockIdx.x * 32, r0 = blockIdx.y * 32;
    int x = threadIdx.x, y = threadIdx.y;
    #pragma unroll
    for (int i = y; i < 32; i += 8) {
        tile[i][x] = src[(size_t)(r0 + i) * C + (c0 + x)];
    }
    __syncthreads();
    #pragma unroll
    for (int i = y; i < 32; i += 8) {
        dst[(size_t)(c0 + i) * R + (r0 + x)] = tile[x][i];
    }
}

// ---------------- ih precompute: pre[t,h,b] = bias_ih[h]+bias_hh[h] + spmm(ih, xT[t]) ----------------
__global__ void __launch_bounds__(128) ih_pre_kernel(
    const int* __restrict__ rp, const int* __restrict__ cols, const float* __restrict__ vals,
    const float* __restrict__ xT, float* __restrict__ pre,
    const float* __restrict__ bias_ih, const float* __restrict__ bias_hh) {
    int id = blockIdx.x;          // id = t*H + r
    int t = id >> 13;             // H = 8192 = 2^13
    int r = id & (H - 1);
    int b = threadIdx.x;
    const float* __restrict__ xt = xT + (size_t)t * H * B;
    float acc = bias_ih[r] + bias_hh[r];
    int s = rp[r], e = rp[r + 1];
    for (int j = s; j < e; ++j) {
        acc = fmaf(vals[j], xt[(size_t)cols[j] * B + b], acc);
    }
    pre[(size_t)id * B + b] = acc;
}

// ---------------- one recurrence step: h_new = tanh(pre_t + spmm(hh, h_prev)); pre_t <- h_new (outT) ----------------
__global__ void __launch_bounds__(128) step_kernel(
    const int* __restrict__ rp, const int* __restrict__ cols, const float* __restrict__ vals,
    const float* __restrict__ hprev, float* __restrict__ hnew, float* __restrict__ pre_t) {
    int r = blockIdx.x;
    int b = threadIdx.x;
    float acc = pre_t[(size_t)r * B + b];
    int s = rp[r], e = rp[r + 1];
    for (int j = s; j < e; ++j) {
        acc = fmaf(vals[j], hprev[(size_t)cols[j] * B + b], acc);
    }
    float h = tanhf(acc);
    hnew[(size_t)r * B + b] = h;
    pre_t[(size_t)r * B + b] = h;   // becomes outT[t][r][b]
}

extern "C" void kernel_launch(void* const* d_in, const int* in_sizes, int n_in,
                              void* d_out, int out_size, void* d_ws, size_t ws_size,
                              hipStream_t stream) {
    const float* x        = (const float*)d_in[0];
    const int*   ih_idx   = (const int*)d_in[1];
    const float* ih_val   = (const float*)d_in[2];
    const int*   hh_idx   = (const int*)d_in[3];
    const float* hh_val   = (const float*)d_in[4];
    const float* bias_ih  = (const float*)d_in[5];
    const float* bias_hh  = (const float*)d_in[6];
    const int* ih_rows = ih_idx;
    const int* ih_cols = ih_idx + NNZ;
    const int* hh_rows = hh_idx;
    const int* hh_cols = hh_idx + NNZ;

    char* ws = (char*)d_ws;
    size_t off = 0;
    auto alloc = [&](size_t bytes) -> void* {
        void* p = ws + off;
        off += (bytes + 255) & ~(size_t)255;
        return p;
    };
    float* xT      = (float*)alloc((size_t)T * H * B * 4);   // 256 MB
    float* pre     = (float*)alloc((size_t)T * H * B * 4);   // 256 MB (becomes outT)
    int*   ccol_ih = (int*)  alloc((size_t)NNZ * 4);
    float* cval_ih = (float*)alloc((size_t)NNZ * 4);
    int*   ccol_hh = (int*)  alloc((size_t)NNZ * 4);
    float* cval_hh = (float*)alloc((size_t)NNZ * 4);
    int*   rp_ih   = (int*)  alloc((size_t)(H + 1) * 4);
    int*   rp_hh   = (int*)  alloc((size_t)(H + 1) * 4);
    int*   cnt_ih  = (int*)  alloc((size_t)H * 4);
    int*   cnt_hh  = (int*)  alloc((size_t)H * 4);
    int*   cur_ih  = (int*)  alloc((size_t)H * 4);
    int*   cur_hh  = (int*)  alloc((size_t)H * 4);
    float* h0      = (float*)alloc((size_t)H * B * 4);
    float* h1      = (float*)alloc((size_t)H * B * 4);

    hipMemsetAsync(cnt_ih, 0, (size_t)H * 4, stream);
    hipMemsetAsync(cnt_hh, 0, (size_t)H * 4, stream);
    hipMemsetAsync(h0, 0, (size_t)H * B * 4, stream);

    const int tb = 256;
    const int gb = (NNZ + tb - 1) / tb;
    hist_kernel<<<gb, tb, 0, stream>>>(ih_rows, NNZ, cnt_ih);
    hist_kernel<<<gb, tb, 0, stream>>>(hh_rows, NNZ, cnt_hh);
    scan_kernel<<<2, 1024, 0, stream>>>(cnt_ih, rp_ih, cur_ih, cnt_hh, rp_hh, cur_hh);
    scatter_kernel<<<gb, tb, 0, stream>>>(ih_rows, ih_cols, ih_val, NNZ, cur_ih, ccol_ih, cval_ih);
    scatter_kernel<<<gb, tb, 0, stream>>>(hh_rows, hh_cols, hh_val, NNZ, cur_hh, ccol_hh, cval_hh);

    // x [B][T*H] -> xT [T*H][B]
    dim3 tblk(32, 8);
    dim3 tgrid1((T * H) / 32, B / 32);
    transpose_kernel<<<tgrid1, tblk, 0, stream>>>(x, xT, B, T * H);

    // all-timestep ih spmm + bias
    ih_pre_kernel<<<T * H, B, 0, stream>>>(rp_ih, ccol_ih, cval_ih, xT, pre, bias_ih, bias_hh);

    // sequential recurrence
    float* hbuf[2] = { h0, h1 };
    for (int t = 0; t < T; ++t) {
        step_kernel<<<H, B, 0, stream>>>(rp_hh, ccol_hh, cval_hh,
                                         hbuf[t & 1], hbuf[(t + 1) & 1],
                                         pre + (size_t)t * H * B);
    }

    // outT [T*H][B] -> d_out [B][T*H]
    dim3 tgrid2(B / 32, (T * H) / 32);
    transpose_kernel<<<tgrid2, tblk, 0, stream>>>(pre, (float*)d_out, T * H, B);
}

// Round 2
// 4721.046 us; speedup vs baseline: 2.2556x; 2.2556x over previous
//
#include <hip/hip_runtime.h>
#include <cstdint>
#include <cstddef>
#include <cstring>

#define H 8192
#define NNZ 1000000
#define B 128
#define T 64

// ---------------- CSR build ----------------
__global__ void hist_kernel(const int* __restrict__ rows, int nnz, int* __restrict__ count) {
    int j = blockIdx.x * blockDim.x + threadIdx.x;
    if (j < nnz) atomicAdd(&count[rows[j]], 1);
}

// grid=2 blocks, 1024 threads: block 0 scans array A, block 1 scans array B.
__global__ void scan_kernel(const int* __restrict__ cnt0, int* __restrict__ rp0, int* __restrict__ cur0,
                            const int* __restrict__ cnt1, int* __restrict__ rp1, int* __restrict__ cur1) {
    const int* cnt = (blockIdx.x == 0) ? cnt0 : cnt1;
    int* rp  = (blockIdx.x == 0) ? rp0 : rp1;
    int* cur = (blockIdx.x == 0) ? cur0 : cur1;
    __shared__ int buf[1024];
    __shared__ int carry;
    int tid = threadIdx.x;
    if (tid == 0) carry = 0;
    __syncthreads();
    for (int base = 0; base < H; base += 1024) {
        int v = cnt[base + tid];
        buf[tid] = v;
        __syncthreads();
        for (int off = 1; off < 1024; off <<= 1) {
            int t = (tid >= off) ? buf[tid - off] : 0;
            __syncthreads();
            buf[tid] += t;
            __syncthreads();
        }
        int incl = buf[tid];
        int excl = incl - v;
        int c = carry;
        rp[base + tid]  = c + excl;
        cur[base + tid] = c + excl;
        __syncthreads();
        if (tid == 1023) carry = c + incl;
        __syncthreads();
    }
    if (tid == 0) rp[H] = carry;
}

__global__ void scatter_kernel(const int* __restrict__ rows, const int* __restrict__ cols,
                               const float* __restrict__ vals, int nnz,
                               int* __restrict__ cursor, int* __restrict__ ocol, float* __restrict__ oval) {
    int j = blockIdx.x * blockDim.x + threadIdx.x;
    if (j < nnz) {
        int r = rows[j];
        int p = atomicAdd(&cursor[r], 1);
        ocol[p] = cols[j];
        oval[p] = vals[j];
    }
}

// ---------------- transpose src[R][C] -> dst[C][R]  (R,C multiples of 32) ----------------
__global__ void transpose_kernel(const float* __restrict__ src, float* __restrict__ dst,
                                 int R, int C) {
    __shared__ float tile[32][33];
    int c0 = blockIdx.x * 32, r0 = blockIdx.y * 32;
    int x = threadIdx.x, y = threadIdx.y;
    #pragma unroll
    for (int i = y; i < 32; i += 8) {
        tile[i][x] = src[(size_t)(r0 + i) * C + (c0 + x)];
    }
    __syncthreads();
    #pragma unroll
    for (int i = y; i < 32; i += 8) {
        dst[(size_t)(c0 + i) * R + (r0 + x)] = tile[x][i];
    }
}

// ---------------- ih precompute: pre[t,h,b] = bias + spmm(ih, xT[t]) ----------------
// 64 threads/block (1 wave), float2 per lane, unroll-8 gather batching.
__global__ void __launch_bounds__(64) ih_pre_kernel(
    const int* __restrict__ rp, const int* __restrict__ cols, const float* __restrict__ vals,
    const float* __restrict__ xT, float* __restrict__ pre,
    const float* __restrict__ bias_ih, const float* __restrict__ bias_hh) {
    int id = blockIdx.x;          // id = t*H + r
    int t = id >> 13;             // H = 8192 = 2^13
    int r = id & (H - 1);
    int b2 = threadIdx.x;         // covers batch elements 2*b2, 2*b2+1
    const float2* __restrict__ xt2 = (const float2*)(xT + (size_t)t * H * B);
    float bias = bias_ih[r] + bias_hh[r];
    float ax = bias, ay = bias;
    int s = rp[r], e = rp[r + 1];
    int j = s;
    for (; j + 8 <= e; j += 8) {
        int   c[8]; float v[8];
        #pragma unroll
        for (int u = 0; u < 8; ++u) { c[u] = cols[j + u]; v[u] = vals[j + u]; }
        float2 g[8];
        #pragma unroll
        for (int u = 0; u < 8; ++u) g[u] = xt2[(size_t)c[u] * 64 + b2];
        #pragma unroll
        for (int u = 0; u < 8; ++u) { ax = fmaf(v[u], g[u].x, ax); ay = fmaf(v[u], g[u].y, ay); }
    }
    for (; j < e; ++j) {
        float2 g = xt2[(size_t)cols[j] * 64 + b2];
        ax = fmaf(vals[j], g.x, ax);
        ay = fmaf(vals[j], g.y, ay);
    }
    float2 o; o.x = ax; o.y = ay;
    double od; __builtin_memcpy(&od, &o, 8);
    __builtin_nontemporal_store(od, (double*)(pre + (size_t)id * B) + b2);
}

// ---------------- one recurrence step ----------------
__global__ void __launch_bounds__(64) step_kernel(
    const int* __restrict__ rp, const int* __restrict__ cols, const float* __restrict__ vals,
    const float* __restrict__ hprev, float* __restrict__ hnew, float* __restrict__ pre_t) {
    int r = blockIdx.x;
    int b2 = threadIdx.x;
    const float2* __restrict__ h2 = (const float2*)hprev;
    double pd = __builtin_nontemporal_load((const double*)(pre_t + (size_t)r * B) + b2);
    float2 p; __builtin_memcpy(&p, &pd, 8);
    float ax = p.x, ay = p.y;
    int s = rp[r], e = rp[r + 1];
    int j = s;
    for (; j + 8 <= e; j += 8) {
        int   c[8]; float v[8];
        #pragma unroll
        for (int u = 0; u < 8; ++u) { c[u] = cols[j + u]; v[u] = vals[j + u]; }
        float2 g[8];
        #pragma unroll
        for (int u = 0; u < 8; ++u) g[u] = h2[(size_t)c[u] * 64 + b2];
        #pragma unroll
        for (int u = 0; u < 8; ++u) { ax = fmaf(v[u], g[u].x, ax); ay = fmaf(v[u], g[u].y, ay); }
    }
    for (; j < e; ++j) {
        float2 g = h2[(size_t)cols[j] * 64 + b2];
        ax = fmaf(vals[j], g.x, ax);
        ay = fmaf(vals[j], g.y, ay);
    }
    float hx = tanhf(ax), hy = tanhf(ay);
    float2 o; o.x = hx; o.y = hy;
    ((float2*)hnew)[(size_t)r * 64 + b2] = o;        // cached: gathered next step
    double od; __builtin_memcpy(&od, &o, 8);
    __builtin_nontemporal_store(od, (double*)(pre_t + (size_t)r * B) + b2);  // streaming outT
}

extern "C" void kernel_launch(void* const* d_in, const int* in_sizes, int n_in,
                              void* d_out, int out_size, void* d_ws, size_t ws_size,
                              hipStream_t stream) {
    const float* x        = (const float*)d_in[0];
    const int*   ih_idx   = (const int*)d_in[1];
    const float* ih_val   = (const float*)d_in[2];
    const int*   hh_idx   = (const int*)d_in[3];
    const float* hh_val   = (const float*)d_in[4];
    const float* bias_ih  = (const float*)d_in[5];
    const float* bias_hh  = (const float*)d_in[6];
    const int* ih_rows = ih_idx;
    const int* ih_cols = ih_idx + NNZ;
    const int* hh_rows = hh_idx;
    const int* hh_cols = hh_idx + NNZ;

    char* ws = (char*)d_ws;
    size_t off = 0;
    auto alloc = [&](size_t bytes) -> void* {
        void* p = ws + off;
        off += (bytes + 255) & ~(size_t)255;
        return p;
    };
    float* xT      = (float*)alloc((size_t)T * H * B * 4);   // 256 MB
    float* pre     = (float*)alloc((size_t)T * H * B * 4);   // 256 MB (becomes outT)
    int*   ccol_ih = (int*)  alloc((size_t)NNZ * 4);
    float* cval_ih = (float*)alloc((size_t)NNZ * 4);
    int*   ccol_hh = (int*)  alloc((size_t)NNZ * 4);
    float* cval_hh = (float*)alloc((size_t)NNZ * 4);
    int*   rp_ih   = (int*)  alloc((size_t)(H + 1) * 4);
    int*   rp_hh   = (int*)  alloc((size_t)(H + 1) * 4);
    int*   cnt_ih  = (int*)  alloc((size_t)H * 4);
    int*   cnt_hh  = (int*)  alloc((size_t)H * 4);
    int*   cur_ih  = (int*)  alloc((size_t)H * 4);
    int*   cur_hh  = (int*)  alloc((size_t)H * 4);
    float* h0      = (float*)alloc((size_t)H * B * 4);
    float* h1      = (float*)alloc((size_t)H * B * 4);

    hipMemsetAsync(cnt_ih, 0, (size_t)H * 4, stream);
    hipMemsetAsync(cnt_hh, 0, (size_t)H * 4, stream);
    hipMemsetAsync(h0, 0, (size_t)H * B * 4, stream);

    const int tb = 256;
    const int gb = (NNZ + tb - 1) / tb;
    hist_kernel<<<gb, tb, 0, stream>>>(ih_rows, NNZ, cnt_ih);
    hist_kernel<<<gb, tb, 0, stream>>>(hh_rows, NNZ, cnt_hh);
    scan_kernel<<<2, 1024, 0, stream>>>(cnt_ih, rp_ih, cur_ih, cnt_hh, rp_hh, cur_hh);
    scatter_kernel<<<gb, tb, 0, stream>>>(ih_rows, ih_cols, ih_val, NNZ, cur_ih, ccol_ih, cval_ih);
    scatter_kernel<<<gb, tb, 0, stream>>>(hh_rows, hh_cols, hh_val, NNZ, cur_hh, ccol_hh, cval_hh);

    // x [B][T*H] -> xT [T*H][B]
    dim3 tblk(32, 8);
    dim3 tgrid1((T * H) / 32, B / 32);
    transpose_kernel<<<tgrid1, tblk, 0, stream>>>(x, xT, B, T * H);

    // all-timestep ih spmm + bias
    ih_pre_kernel<<<T * H, 64, 0, stream>>>(rp_ih, ccol_ih, cval_ih, xT, pre, bias_ih, bias_hh);

    // sequential recurrence
    float* hbuf[2] = { h0, h1 };
    for (int t = 0; t < T; ++t) {
        step_kernel<<<H, 64, 0, stream>>>(rp_hh, ccol_hh, cval_hh,
                                          hbuf[t & 1], hbuf[(t + 1) & 1],
                                          pre + (size_t)t * H * B);
    }

    // outT [T*H][B] -> d_out [B][T*H]
    dim3 tgrid2(B / 32, (T * H) / 32);
    transpose_kernel<<<tgrid2, tblk, 0, stream>>>(pre, (float*)d_out, T * H, B);
}